// Round 1
// baseline (1390.498 us; speedup 1.0000x reference)
//
#include <hip/hip_runtime.h>

#define F 128  // IN_FEATS == OUT_FEATS

// ---------------------------------------------------------------- zero d_out
__global__ void zero_f4(float4* __restrict__ p, int n4) {
  int i = blockIdx.x * blockDim.x + threadIdx.x;
  if (i < n4) p[i] = make_float4(0.f, 0.f, 0.f, 0.f);
}

// ------------------------------------------------- edge gather + scatter-add
// 32 threads per edge; each thread moves one float4 (16B) of the 512B row.
__global__ __launch_bounds__(256) void scatter_add(
    const float* __restrict__ feat, const int* __restrict__ src,
    const int* __restrict__ dst, float* __restrict__ h, int n_edges) {
  long long gid = (long long)blockIdx.x * 256 + threadIdx.x;
  int e = (int)(gid >> 5);
  if (e >= n_edges) return;
  int c = (int)(gid & 31);
  int s = src[e];  // same address across the 32-lane group -> broadcast
  int d = dst[e];
  float4 v = reinterpret_cast<const float4*>(feat + (long long)s * F)[c];
  float* hp = h + (long long)d * F + c * 4;
  __hip_atomic_fetch_add(hp + 0, v.x, __ATOMIC_RELAXED, __HIP_MEMORY_SCOPE_AGENT);
  __hip_atomic_fetch_add(hp + 1, v.y, __ATOMIC_RELAXED, __HIP_MEMORY_SCOPE_AGENT);
  __hip_atomic_fetch_add(hp + 2, v.z, __ATOMIC_RELAXED, __HIP_MEMORY_SCOPE_AGENT);
  __hip_atomic_fetch_add(hp + 3, v.w, __ATOMIC_RELAXED, __HIP_MEMORY_SCOPE_AGENT);
}

// --------------------------------------------- in-place h -> h @ W^T + bias
// 128 threads/block; thread j owns output feature j and keeps W[j][:] in
// 32 float4 registers. h rows are wave-uniform loads (L1 broadcast).
// __syncthreads() separates "all lanes read rows r..r+3" from the in-place
// overwrite of those rows.
__global__ __launch_bounds__(128) void linear_inplace(
    float* __restrict__ hout, const float* __restrict__ W,
    const float* __restrict__ bias, int n_rows, int rows_per_block) {
  const int j = threadIdx.x;
  int r0 = blockIdx.x * rows_per_block;
  int r1 = r0 + rows_per_block;
  if (r1 > n_rows) r1 = n_rows;
  if (r0 >= r1) return;

  float4 w[F / 4];
  const float4* wp = reinterpret_cast<const float4*>(W + (size_t)j * F);
#pragma unroll
  for (int q = 0; q < F / 4; ++q) w[q] = wp[q];
  const float bj = bias[j];

  for (int r = r0; r < r1; r += 4) {
    const int nr = (r1 - r) < 4 ? (r1 - r) : 4;  // block-uniform
    float acc[4] = {bj, bj, bj, bj};
    const float4* hp0 = reinterpret_cast<const float4*>(hout + (size_t)r * F);
    if (nr == 4) {
#pragma unroll
      for (int q = 0; q < F / 4; ++q) {
        float4 a = hp0[q];
        float4 b = hp0[32 + q];
        float4 c = hp0[64 + q];
        float4 d = hp0[96 + q];
        acc[0] += w[q].x * a.x + w[q].y * a.y + w[q].z * a.z + w[q].w * a.w;
        acc[1] += w[q].x * b.x + w[q].y * b.y + w[q].z * b.z + w[q].w * b.w;
        acc[2] += w[q].x * c.x + w[q].y * c.y + w[q].z * c.z + w[q].w * c.w;
        acc[3] += w[q].x * d.x + w[q].y * d.y + w[q].z * d.z + w[q].w * d.w;
      }
    } else {
      for (int t = 0; t < nr; ++t) {
        const float4* hp = reinterpret_cast<const float4*>(hout + (size_t)(r + t) * F);
#pragma unroll
        for (int q = 0; q < F / 4; ++q) {
          float4 a = hp[q];
          acc[t] += w[q].x * a.x + w[q].y * a.y + w[q].z * a.z + w[q].w * a.w;
        }
      }
    }
    __syncthreads();  // all reads of rows r..r+nr-1 done before overwrite
    for (int t = 0; t < nr; ++t)
      hout[(size_t)(r + t) * F + j] = acc[t];
  }
}

extern "C" void kernel_launch(void* const* d_in, const int* in_sizes, int n_in,
                              void* d_out, int out_size, void* d_ws, size_t ws_size,
                              hipStream_t stream) {
  const float* feat = (const float*)d_in[0];
  const int* esrc   = (const int*)d_in[1];
  const int* edst   = (const int*)d_in[2];
  const float* W    = (const float*)d_in[3];
  const float* bias = (const float*)d_in[4];
  float* out = (float*)d_out;

  const int n_edges = in_sizes[1];
  const int n_rows  = out_size / F;  // 100000

  // 1) zero the accumulator (d_out doubles as h)
  int n4 = out_size / 4;
  zero_f4<<<(n4 + 255) / 256, 256, 0, stream>>>((float4*)out, n4);

  // 2) scatter-add messages
  long long total = (long long)n_edges * 32;
  int blocks = (int)((total + 255) / 256);
  scatter_add<<<blocks, 256, 0, stream>>>(feat, esrc, edst, out, n_edges);

  // 3) in-place linear transform
  const int rpb = 100;
  linear_inplace<<<(n_rows + rpb - 1) / rpb, 128, 0, stream>>>(out, W, bias,
                                                               n_rows, rpb);
}

// Round 2
// 319.110 us; speedup vs baseline: 4.3574x; 4.3574x over previous
//
#include <hip/hip_runtime.h>

#define F 128  // IN_FEATS == OUT_FEATS
#define SCAN_BLK 256
#define SCAN_ELEMS 4
#define SCAN_TILE 1024  // SCAN_BLK * SCAN_ELEMS

// ------------------------------------------------------------ small helpers
__global__ void zero_int(int* __restrict__ p, int n) {
  int i = blockIdx.x * blockDim.x + threadIdx.x;
  if (i < n) p[i] = 0;
}

__global__ void zero_f4(float4* __restrict__ p, int n4) {
  int i = blockIdx.x * blockDim.x + threadIdx.x;
  if (i < n4) p[i] = make_float4(0.f, 0.f, 0.f, 0.f);
}

// ------------------------------------------------------------- degree count
__global__ void count_deg(const int* __restrict__ dst, int* __restrict__ deg,
                          int nE) {
  int e = blockIdx.x * blockDim.x + threadIdx.x;
  if (e < nE) atomicAdd(&deg[dst[e]], 1);
}

// --------------------------------------------------- 3-kernel exclusive scan
__global__ __launch_bounds__(SCAN_BLK) void scan1(const int* __restrict__ deg,
                                                  int* __restrict__ roff,
                                                  int* __restrict__ bsum,
                                                  int n) {
  __shared__ int sd[SCAN_BLK];
  const int tid = threadIdx.x;
  const int base = blockIdx.x * SCAN_TILE + tid * SCAN_ELEMS;
  int v[SCAN_ELEMS];
  int s = 0;
#pragma unroll
  for (int k = 0; k < SCAN_ELEMS; ++k) {
    int i = base + k;
    v[k] = (i < n) ? deg[i] : 0;
    s += v[k];
  }
  sd[tid] = s;
  __syncthreads();
  for (int off = 1; off < SCAN_BLK; off <<= 1) {
    int t = (tid >= off) ? sd[tid - off] : 0;
    __syncthreads();
    sd[tid] += t;
    __syncthreads();
  }
  int excl = sd[tid] - s;
  if (tid == SCAN_BLK - 1) bsum[blockIdx.x] = sd[tid];
  int p = excl;
#pragma unroll
  for (int k = 0; k < SCAN_ELEMS; ++k) {
    int i = base + k;
    if (i < n) roff[i] = p;
    p += v[k];
  }
}

__global__ __launch_bounds__(SCAN_BLK) void scan2(int* __restrict__ bsum,
                                                  int nb) {
  __shared__ int sd[SCAN_BLK];
  const int tid = threadIdx.x;
  int s = (tid < nb) ? bsum[tid] : 0;
  sd[tid] = s;
  __syncthreads();
  for (int off = 1; off < SCAN_BLK; off <<= 1) {
    int t = (tid >= off) ? sd[tid - off] : 0;
    __syncthreads();
    sd[tid] += t;
    __syncthreads();
  }
  if (tid < nb) bsum[tid] = sd[tid] - s;  // exclusive block offsets
}

__global__ void scan3(int* __restrict__ roff, int* __restrict__ cur,
                      const int* __restrict__ bsum, int n, int nE) {
  int i = blockIdx.x * blockDim.x + threadIdx.x;
  if (i < n) {
    int v = roff[i] + bsum[i / SCAN_TILE];
    roff[i] = v;
    cur[i] = v;
  }
  if (i == 0) roff[n] = nE;
}

// ------------------------------------------------------------ CSR scatter
__global__ void build_csr(const int* __restrict__ src,
                          const int* __restrict__ dst, int* __restrict__ cur,
                          int* __restrict__ csr, int nE) {
  int e = blockIdx.x * blockDim.x + threadIdx.x;
  if (e >= nE) return;
  int d = dst[e];
  int pos = atomicAdd(&cur[d], 1);
  csr[pos] = src[e];
}

// ------------------------------------------- conflict-free node aggregation
// one 64-lane wave per node; lane holds float2 (8B) of the 512B row.
__global__ __launch_bounds__(256) void aggregate(
    const float* __restrict__ feat, const int* __restrict__ roff,
    const int* __restrict__ csr, float* __restrict__ h, int n_nodes) {
  int node = (int)((blockIdx.x * 256u + threadIdx.x) >> 6);
  int lane = threadIdx.x & 63;
  if (node >= n_nodes) return;
  int beg = roff[node], end = roff[node + 1];
  float ax = 0.f, ay = 0.f;
  const float2* f2 = (const float2*)feat;
  int k = beg;
  for (; k + 1 < end; k += 2) {
    int s0 = csr[k], s1 = csr[k + 1];
    float2 v0 = f2[(size_t)s0 * 64 + lane];
    float2 v1 = f2[(size_t)s1 * 64 + lane];
    ax += v0.x + v1.x;
    ay += v0.y + v1.y;
  }
  if (k < end) {
    int s0 = csr[k];
    float2 v0 = f2[(size_t)s0 * 64 + lane];
    ax += v0.x;
    ay += v0.y;
  }
  float2 o;
  o.x = ax;
  o.y = ay;
  ((float2*)h)[(size_t)node * 64 + lane] = o;
}

// --------------------- fallback atomic scatter (only if ws too small) ------
__global__ __launch_bounds__(256) void scatter_add(
    const float* __restrict__ feat, const int* __restrict__ src,
    const int* __restrict__ dst, float* __restrict__ h, int n_edges) {
  long long gid = (long long)blockIdx.x * 256 + threadIdx.x;
  int e = (int)(gid >> 5);
  if (e >= n_edges) return;
  int c = (int)(gid & 31);
  int s = src[e];
  int d = dst[e];
  float4 v = reinterpret_cast<const float4*>(feat + (long long)s * F)[c];
  float* hp = h + (long long)d * F + c * 4;
  __hip_atomic_fetch_add(hp + 0, v.x, __ATOMIC_RELAXED, __HIP_MEMORY_SCOPE_AGENT);
  __hip_atomic_fetch_add(hp + 1, v.y, __ATOMIC_RELAXED, __HIP_MEMORY_SCOPE_AGENT);
  __hip_atomic_fetch_add(hp + 2, v.z, __ATOMIC_RELAXED, __HIP_MEMORY_SCOPE_AGENT);
  __hip_atomic_fetch_add(hp + 3, v.w, __ATOMIC_RELAXED, __HIP_MEMORY_SCOPE_AGENT);
}

// --------------------------------------------- in-place h -> h @ W^T + bias
// 128 threads/block; thread j owns output feature j, W[j][:] in registers.
// 4 h-rows staged in LDS via coalesced float4 loads (128 thr x 16B = 4 rows).
__global__ __launch_bounds__(128) void linear_lds(float* __restrict__ hout,
                                                  const float* __restrict__ W,
                                                  const float* __restrict__ bias,
                                                  int n_rows) {
  __shared__ float tile[4 * F];
  const int j = threadIdx.x;
  float4 w[F / 4];
  const float4* wp = (const float4*)(W + (size_t)j * F);
#pragma unroll
  for (int q = 0; q < F / 4; ++q) w[q] = wp[q];
  const float bj = bias[j];
  const int ngroups = (n_rows + 3) >> 2;
  for (int g = blockIdx.x; g < ngroups; g += gridDim.x) {
    const int r = g << 2;
    const int nr = min(4, n_rows - r);
    float4 v = make_float4(0.f, 0.f, 0.f, 0.f);
    if (j < nr * 32) v = ((const float4*)(hout + (size_t)r * F))[j];
    __syncthreads();  // previous group's tile reads complete
    ((float4*)tile)[j] = v;
    __syncthreads();
    float a0 = bj, a1 = bj, a2 = bj, a3 = bj;
    const float4* t4 = (const float4*)tile;
#pragma unroll
    for (int q = 0; q < F / 4; ++q) {
      float4 x0 = t4[q];
      float4 x1 = t4[32 + q];
      float4 x2 = t4[64 + q];
      float4 x3 = t4[96 + q];
      a0 += w[q].x * x0.x + w[q].y * x0.y + w[q].z * x0.z + w[q].w * x0.w;
      a1 += w[q].x * x1.x + w[q].y * x1.y + w[q].z * x1.z + w[q].w * x1.w;
      a2 += w[q].x * x2.x + w[q].y * x2.y + w[q].z * x2.z + w[q].w * x2.w;
      a3 += w[q].x * x3.x + w[q].y * x3.y + w[q].z * x3.z + w[q].w * x3.w;
    }
    if (nr == 4) {
      hout[(size_t)r * F + j] = a0;
      hout[(size_t)(r + 1) * F + j] = a1;
      hout[(size_t)(r + 2) * F + j] = a2;
      hout[(size_t)(r + 3) * F + j] = a3;
    } else {
      float acc[4] = {a0, a1, a2, a3};
      for (int t = 0; t < nr; ++t) hout[(size_t)(r + t) * F + j] = acc[t];
    }
  }
}

static inline size_t align_up(size_t x, size_t a) { return (x + a - 1) & ~(a - 1); }

extern "C" void kernel_launch(void* const* d_in, const int* in_sizes, int n_in,
                              void* d_out, int out_size, void* d_ws, size_t ws_size,
                              hipStream_t stream) {
  const float* feat = (const float*)d_in[0];
  const int* esrc   = (const int*)d_in[1];
  const int* edst   = (const int*)d_in[2];
  const float* W    = (const float*)d_in[3];
  const float* bias = (const float*)d_in[4];
  float* out = (float*)d_out;

  const int nE = in_sizes[1];
  const int nN = out_size / F;  // 100000

  // workspace layout
  size_t off_deg  = 0;
  size_t off_roff = align_up(off_deg + (size_t)nN * 4, 256);
  size_t off_cur  = align_up(off_roff + ((size_t)nN + 1) * 4, 256);
  size_t off_bsum = align_up(off_cur + (size_t)nN * 4, 256);
  size_t off_csr  = align_up(off_bsum + 1024 * 4, 256);
  size_t need     = off_csr + (size_t)nE * 4;
  const int nb = (nN + SCAN_TILE - 1) / SCAN_TILE;

  if (ws_size >= need && nb <= SCAN_BLK) {
    char* w = (char*)d_ws;
    int* deg  = (int*)(w + off_deg);
    int* roff = (int*)(w + off_roff);
    int* cur  = (int*)(w + off_cur);
    int* bsum = (int*)(w + off_bsum);
    int* csr  = (int*)(w + off_csr);

    zero_int<<<(nN + 255) / 256, 256, 0, stream>>>(deg, nN);
    count_deg<<<(nE + 255) / 256, 256, 0, stream>>>(edst, deg, nE);
    scan1<<<nb, SCAN_BLK, 0, stream>>>(deg, roff, bsum, nN);
    scan2<<<1, SCAN_BLK, 0, stream>>>(bsum, nb);
    scan3<<<(nN + 255) / 256, 256, 0, stream>>>(roff, cur, bsum, nN, nE);
    build_csr<<<(nE + 255) / 256, 256, 0, stream>>>(esrc, edst, cur, csr, nE);

    long long waves = (long long)nN * 64;
    aggregate<<<(int)((waves + 255) / 256), 256, 0, stream>>>(feat, roff, csr,
                                                              out, nN);
  } else {
    // fallback: atomic scatter path (round-1)
    int n4 = out_size / 4;
    zero_f4<<<(n4 + 255) / 256, 256, 0, stream>>>((float4*)out, n4);
    long long total = (long long)nE * 32;
    scatter_add<<<(int)((total + 255) / 256), 256, 0, stream>>>(feat, esrc,
                                                                edst, out, nE);
  }

  linear_lds<<<2048, 128, 0, stream>>>(out, W, bias, nN);
}

// Round 3
// 173.740 us; speedup vs baseline: 8.0033x; 1.8367x over previous
//
#include <hip/hip_runtime.h>

#define F 128  // IN_FEATS == OUT_FEATS
#define SCAN_BLK 256
#define SCAN_ELEMS 4
#define SCAN_TILE 1024  // SCAN_BLK * SCAN_ELEMS

typedef __bf16 bf8 __attribute__((ext_vector_type(8)));
typedef float f4 __attribute__((ext_vector_type(4)));

// ------------------------------------------------------------ small helpers
__global__ void zero_int(int* __restrict__ p, int n) {
  int i = blockIdx.x * blockDim.x + threadIdx.x;
  if (i < n) p[i] = 0;
}

__global__ void zero_f4(float4* __restrict__ p, int n4) {
  int i = blockIdx.x * blockDim.x + threadIdx.x;
  if (i < n4) p[i] = make_float4(0.f, 0.f, 0.f, 0.f);
}

// ------------------------------------------------------------- degree count
__global__ void count_deg(const int* __restrict__ dst, int* __restrict__ deg,
                          int nE) {
  int e = blockIdx.x * blockDim.x + threadIdx.x;
  if (e < nE) atomicAdd(&deg[dst[e]], 1);
}

// --------------------------------------------------- 3-kernel exclusive scan
__global__ __launch_bounds__(SCAN_BLK) void scan1(const int* __restrict__ deg,
                                                  int* __restrict__ roff,
                                                  int* __restrict__ bsum,
                                                  int n) {
  __shared__ int sd[SCAN_BLK];
  const int tid = threadIdx.x;
  const int base = blockIdx.x * SCAN_TILE + tid * SCAN_ELEMS;
  int v[SCAN_ELEMS];
  int s = 0;
#pragma unroll
  for (int k = 0; k < SCAN_ELEMS; ++k) {
    int i = base + k;
    v[k] = (i < n) ? deg[i] : 0;
    s += v[k];
  }
  sd[tid] = s;
  __syncthreads();
  for (int off = 1; off < SCAN_BLK; off <<= 1) {
    int t = (tid >= off) ? sd[tid - off] : 0;
    __syncthreads();
    sd[tid] += t;
    __syncthreads();
  }
  int excl = sd[tid] - s;
  if (tid == SCAN_BLK - 1) bsum[blockIdx.x] = sd[tid];
  int p = excl;
#pragma unroll
  for (int k = 0; k < SCAN_ELEMS; ++k) {
    int i = base + k;
    if (i < n) roff[i] = p;
    p += v[k];
  }
}

__global__ __launch_bounds__(SCAN_BLK) void scan2(int* __restrict__ bsum,
                                                  int nb) {
  __shared__ int sd[SCAN_BLK];
  const int tid = threadIdx.x;
  int s = (tid < nb) ? bsum[tid] : 0;
  sd[tid] = s;
  __syncthreads();
  for (int off = 1; off < SCAN_BLK; off <<= 1) {
    int t = (tid >= off) ? sd[tid - off] : 0;
    __syncthreads();
    sd[tid] += t;
    __syncthreads();
  }
  if (tid < nb) bsum[tid] = sd[tid] - s;  // exclusive block offsets
}

__global__ void scan3(int* __restrict__ roff, int* __restrict__ cur,
                      const int* __restrict__ bsum, int n, int nE) {
  int i = blockIdx.x * blockDim.x + threadIdx.x;
  if (i < n) {
    int v = roff[i] + bsum[i / SCAN_TILE];
    roff[i] = v;
    cur[i] = v;
  }
  if (i == 0) roff[n] = nE;
}

// ------------------------------------------------------------ CSR scatter
__global__ void build_csr(const int* __restrict__ src,
                          const int* __restrict__ dst, int* __restrict__ cur,
                          int* __restrict__ csr, int nE) {
  int e = blockIdx.x * blockDim.x + threadIdx.x;
  if (e >= nE) return;
  int d = dst[e];
  int pos = atomicAdd(&cur[d], 1);
  csr[pos] = src[e];
}

// ------------------------------------------- conflict-free node aggregation
// 32 lanes per node; lane c holds float4 c (16B) of the 512B row.
__global__ __launch_bounds__(256) void aggregate(
    const float* __restrict__ feat, const int* __restrict__ roff,
    const int* __restrict__ csr, float* __restrict__ h, int n_nodes) {
  long long gid = (long long)blockIdx.x * 256 + threadIdx.x;
  int node = (int)(gid >> 5);
  int c = (int)(gid & 31);
  if (node >= n_nodes) return;
  int beg = roff[node], end = roff[node + 1];
  float ax = 0.f, ay = 0.f, az = 0.f, aw = 0.f;
  const float4* f4p = (const float4*)feat;
  int k = beg;
  for (; k + 1 < end; k += 2) {
    int s0 = csr[k], s1 = csr[k + 1];
    float4 v0 = f4p[(size_t)s0 * 32 + c];
    float4 v1 = f4p[(size_t)s1 * 32 + c];
    ax += v0.x + v1.x;
    ay += v0.y + v1.y;
    az += v0.z + v1.z;
    aw += v0.w + v1.w;
  }
  if (k < end) {
    int s0 = csr[k];
    float4 v0 = f4p[(size_t)s0 * 32 + c];
    ax += v0.x;
    ay += v0.y;
    az += v0.z;
    aw += v0.w;
  }
  ((float4*)h)[(size_t)node * 32 + c] = make_float4(ax, ay, az, aw);
}

// --------------------- fallback atomic scatter (only if ws too small) ------
__global__ __launch_bounds__(256) void scatter_add(
    const float* __restrict__ feat, const int* __restrict__ src,
    const int* __restrict__ dst, float* __restrict__ h, int n_edges) {
  long long gid = (long long)blockIdx.x * 256 + threadIdx.x;
  int e = (int)(gid >> 5);
  if (e >= n_edges) return;
  int c = (int)(gid & 31);
  int s = src[e];
  int d = dst[e];
  float4 v = reinterpret_cast<const float4*>(feat + (long long)s * F)[c];
  float* hp = h + (long long)d * F + c * 4;
  __hip_atomic_fetch_add(hp + 0, v.x, __ATOMIC_RELAXED, __HIP_MEMORY_SCOPE_AGENT);
  __hip_atomic_fetch_add(hp + 1, v.y, __ATOMIC_RELAXED, __HIP_MEMORY_SCOPE_AGENT);
  __hip_atomic_fetch_add(hp + 2, v.z, __ATOMIC_RELAXED, __HIP_MEMORY_SCOPE_AGENT);
  __hip_atomic_fetch_add(hp + 3, v.w, __ATOMIC_RELAXED, __HIP_MEMORY_SCOPE_AGENT);
}

// --------------------------------------- in-place MFMA: h -> h @ W^T + bias
// 4 waves/block; each wave owns 16 rows per group, all 128 output cols.
// W held entirely in registers as bf16 B-fragments (reused across groups).
// Fragment layout (mfma_f32_16x16x32_bf16, m92/m97-verified lineage):
//   A: row = lane&15, k = (lane>>4)*8 + elem (8 contiguous k)
//   B: col = lane&15, same k indexing
//   C/D: col = lane&15, row = (lane>>4)*4 + reg
__global__ __launch_bounds__(256, 2) void gemm_bias_inplace(
    float* __restrict__ hout, const float* __restrict__ W,
    const float* __restrict__ bias, int n_rows, int n_groups) {
  const int lane = threadIdx.x & 63;
  const int wid = threadIdx.x >> 6;
  const int lr = lane & 15;
  const int lk = (lane >> 4) * 8;

  // ---- W fragments: wf[t][kk] = B-frag for n-tile t, k-step kk
  bf8 wf[8][4];
#pragma unroll
  for (int t = 0; t < 8; ++t) {
    const float* wr = W + (size_t)(t * 16 + lr) * F;
#pragma unroll
    for (int kk = 0; kk < 4; ++kk) {
      float4 u0 = *(const float4*)(wr + kk * 32 + lk);
      float4 u1 = *(const float4*)(wr + kk * 32 + lk + 4);
      bf8 b;
      b[0] = (__bf16)u0.x; b[1] = (__bf16)u0.y;
      b[2] = (__bf16)u0.z; b[3] = (__bf16)u0.w;
      b[4] = (__bf16)u1.x; b[5] = (__bf16)u1.y;
      b[6] = (__bf16)u1.z; b[7] = (__bf16)u1.w;
      wf[t][kk] = b;
    }
  }
  float bj[8];
#pragma unroll
  for (int t = 0; t < 8; ++t) bj[t] = bias[t * 16 + lr];

  for (int g = blockIdx.x; g < n_groups; g += gridDim.x) {
    const int r0 = g * 64 + wid * 16;  // wave-uniform
    if (r0 >= n_rows) continue;

    // ---- A fragments: this wave's 16 rows, bf16-converted on the fly
    int arow = r0 + lr;
    if (arow >= n_rows) arow = n_rows - 1;  // clamp (tail), stores guarded
    const float* hr = hout + (size_t)arow * F;
    bf8 af[4];
#pragma unroll
    for (int kk = 0; kk < 4; ++kk) {
      float4 u0 = *(const float4*)(hr + kk * 32 + lk);
      float4 u1 = *(const float4*)(hr + kk * 32 + lk + 4);
      bf8 a;
      a[0] = (__bf16)u0.x; a[1] = (__bf16)u0.y;
      a[2] = (__bf16)u0.z; a[3] = (__bf16)u0.w;
      a[4] = (__bf16)u1.x; a[5] = (__bf16)u1.y;
      a[6] = (__bf16)u1.z; a[7] = (__bf16)u1.w;
      af[kk] = a;
    }

    f4 acc[8];
#pragma unroll
    for (int t = 0; t < 8; ++t) {
      f4 c = {bj[t], bj[t], bj[t], bj[t]};
      acc[t] = c;
    }
#pragma unroll
    for (int kk = 0; kk < 4; ++kk)
#pragma unroll
      for (int t = 0; t < 8; ++t)
        acc[t] = __builtin_amdgcn_mfma_f32_16x16x32_bf16(af[kk], wf[t][kk],
                                                         acc[t], 0, 0, 0);

    // ---- in-place store (wave wrote only its own 16 rows; no hazard)
    const int rbase = r0 + (lane >> 4) * 4;
#pragma unroll
    for (int t = 0; t < 8; ++t) {
#pragma unroll
      for (int i = 0; i < 4; ++i) {
        int r = rbase + i;
        if (r < n_rows) hout[(size_t)r * F + t * 16 + lr] = acc[t][i];
      }
    }
  }
}

static inline size_t align_up(size_t x, size_t a) { return (x + a - 1) & ~(a - 1); }

extern "C" void kernel_launch(void* const* d_in, const int* in_sizes, int n_in,
                              void* d_out, int out_size, void* d_ws, size_t ws_size,
                              hipStream_t stream) {
  const float* feat = (const float*)d_in[0];
  const int* esrc   = (const int*)d_in[1];
  const int* edst   = (const int*)d_in[2];
  const float* W    = (const float*)d_in[3];
  const float* bias = (const float*)d_in[4];
  float* out = (float*)d_out;

  const int nE = in_sizes[1];
  const int nN = out_size / F;  // 100000

  // workspace layout
  size_t off_deg  = 0;
  size_t off_roff = align_up(off_deg + (size_t)nN * 4, 256);
  size_t off_cur  = align_up(off_roff + ((size_t)nN + 1) * 4, 256);
  size_t off_bsum = align_up(off_cur + (size_t)nN * 4, 256);
  size_t off_csr  = align_up(off_bsum + 1024 * 4, 256);
  size_t need     = off_csr + (size_t)nE * 4;
  const int nb = (nN + SCAN_TILE - 1) / SCAN_TILE;

  if (ws_size >= need && nb <= SCAN_BLK) {
    char* w = (char*)d_ws;
    int* deg  = (int*)(w + off_deg);
    int* roff = (int*)(w + off_roff);
    int* cur  = (int*)(w + off_cur);
    int* bsum = (int*)(w + off_bsum);
    int* csr  = (int*)(w + off_csr);

    zero_int<<<(nN + 255) / 256, 256, 0, stream>>>(deg, nN);
    count_deg<<<(nE + 255) / 256, 256, 0, stream>>>(edst, deg, nE);
    scan1<<<nb, SCAN_BLK, 0, stream>>>(deg, roff, bsum, nN);
    scan2<<<1, SCAN_BLK, 0, stream>>>(bsum, nb);
    scan3<<<(nN + 255) / 256, 256, 0, stream>>>(roff, cur, bsum, nN, nE);
    build_csr<<<(nE + 255) / 256, 256, 0, stream>>>(esrc, edst, cur, csr, nE);

    long long thr = (long long)nN * 32;
    aggregate<<<(int)((thr + 255) / 256), 256, 0, stream>>>(feat, roff, csr,
                                                            out, nN);
  } else {
    // fallback: atomic scatter path
    int n4 = out_size / 4;
    zero_f4<<<(n4 + 255) / 256, 256, 0, stream>>>((float4*)out, n4);
    long long total = (long long)nE * 32;
    scatter_add<<<(int)((total + 255) / 256), 256, 0, stream>>>(feat, esrc,
                                                                edst, out, nE);
  }

  const int n_groups = (nN + 63) / 64;
  gemm_bias_inplace<<<640, 256, 0, stream>>>(out, W, bias, nN, n_groups);
}

// Round 4
// 154.004 us; speedup vs baseline: 9.0290x; 1.1282x over previous
//
#include <hip/hip_runtime.h>

#define F 128  // IN_FEATS == OUT_FEATS
#define SCAN_BLK 256
#define SCAN_ELEMS 4
#define SCAN_TILE 1024  // SCAN_BLK * SCAN_ELEMS

typedef __bf16 bf8 __attribute__((ext_vector_type(8)));
typedef float f4 __attribute__((ext_vector_type(4)));

// ------------------------------------------------------------ small helpers
__global__ void zero_int(int* __restrict__ p, int n) {
  int i = blockIdx.x * blockDim.x + threadIdx.x;
  if (i < n) p[i] = 0;
}

__global__ void zero_f4(float4* __restrict__ p, int n4) {
  int i = blockIdx.x * blockDim.x + threadIdx.x;
  if (i < n4) p[i] = make_float4(0.f, 0.f, 0.f, 0.f);
}

// ------------------------------------------------------------- degree count
__global__ void count_deg(const int* __restrict__ dst, int* __restrict__ deg,
                          int nE) {
  int e = blockIdx.x * blockDim.x + threadIdx.x;
  if (e < nE) atomicAdd(&deg[dst[e]], 1);
}

// --------------------------------------------------- 3-kernel exclusive scan
__global__ __launch_bounds__(SCAN_BLK) void scan1(const int* __restrict__ deg,
                                                  int* __restrict__ roff,
                                                  int* __restrict__ bsum,
                                                  int n) {
  __shared__ int sd[SCAN_BLK];
  const int tid = threadIdx.x;
  const int base = blockIdx.x * SCAN_TILE + tid * SCAN_ELEMS;
  int v[SCAN_ELEMS];
  int s = 0;
#pragma unroll
  for (int k = 0; k < SCAN_ELEMS; ++k) {
    int i = base + k;
    v[k] = (i < n) ? deg[i] : 0;
    s += v[k];
  }
  sd[tid] = s;
  __syncthreads();
  for (int off = 1; off < SCAN_BLK; off <<= 1) {
    int t = (tid >= off) ? sd[tid - off] : 0;
    __syncthreads();
    sd[tid] += t;
    __syncthreads();
  }
  int excl = sd[tid] - s;
  if (tid == SCAN_BLK - 1) bsum[blockIdx.x] = sd[tid];
  int p = excl;
#pragma unroll
  for (int k = 0; k < SCAN_ELEMS; ++k) {
    int i = base + k;
    if (i < n) roff[i] = p;
    p += v[k];
  }
}

__global__ __launch_bounds__(SCAN_BLK) void scan2(int* __restrict__ bsum,
                                                  int nb) {
  __shared__ int sd[SCAN_BLK];
  const int tid = threadIdx.x;
  int s = (tid < nb) ? bsum[tid] : 0;
  sd[tid] = s;
  __syncthreads();
  for (int off = 1; off < SCAN_BLK; off <<= 1) {
    int t = (tid >= off) ? sd[tid - off] : 0;
    __syncthreads();
    sd[tid] += t;
    __syncthreads();
  }
  if (tid < nb) bsum[tid] = sd[tid] - s;  // exclusive block offsets
}

__global__ void scan3(int* __restrict__ roff, int* __restrict__ cur,
                      const int* __restrict__ bsum, int n, int nE) {
  int i = blockIdx.x * blockDim.x + threadIdx.x;
  if (i < n) {
    int v = roff[i] + bsum[i / SCAN_TILE];
    roff[i] = v;
    cur[i] = v;
  }
  if (i == 0) roff[n] = nE;
}

// ------------------------------------------------------------ CSR scatter
__global__ void build_csr(const int* __restrict__ src,
                          const int* __restrict__ dst, int* __restrict__ cur,
                          int* __restrict__ csr, int nE) {
  int e = blockIdx.x * blockDim.x + threadIdx.x;
  if (e >= nE) return;
  int d = dst[e];
  int pos = atomicAdd(&cur[d], 1);
  csr[pos] = src[e];
}

// ------------------------- transform-first: tfeat = bf16(feat @ W^T), no bias
// Fragment layout (mfma_f32_16x16x32_bf16, verified in R3):
//   A: row = lane&15, k = (lane>>4)*8 + elem; B: col = lane&15, same k
//   C/D: col = lane&15, row = (lane>>4)*4 + reg
__global__ __launch_bounds__(256, 2) void transform_bf16(
    const float* __restrict__ feat, const float* __restrict__ W,
    __bf16* __restrict__ tf, int n_rows, int n_groups) {
  const int lane = threadIdx.x & 63;
  const int wid = threadIdx.x >> 6;
  const int lr = lane & 15;
  const int lk = (lane >> 4) * 8;

  bf8 wf[8][4];
#pragma unroll
  for (int t = 0; t < 8; ++t) {
    const float* wr = W + (size_t)(t * 16 + lr) * F;
#pragma unroll
    for (int kk = 0; kk < 4; ++kk) {
      float4 u0 = *(const float4*)(wr + kk * 32 + lk);
      float4 u1 = *(const float4*)(wr + kk * 32 + lk + 4);
      bf8 b;
      b[0] = (__bf16)u0.x; b[1] = (__bf16)u0.y;
      b[2] = (__bf16)u0.z; b[3] = (__bf16)u0.w;
      b[4] = (__bf16)u1.x; b[5] = (__bf16)u1.y;
      b[6] = (__bf16)u1.z; b[7] = (__bf16)u1.w;
      wf[t][kk] = b;
    }
  }

  for (int g = blockIdx.x; g < n_groups; g += gridDim.x) {
    const int r0 = g * 64 + wid * 16;  // wave-uniform
    if (r0 >= n_rows) continue;
    int arow = r0 + lr;
    if (arow >= n_rows) arow = n_rows - 1;  // clamp; stores guarded
    const float* hr = feat + (size_t)arow * F;
    bf8 af[4];
#pragma unroll
    for (int kk = 0; kk < 4; ++kk) {
      float4 u0 = *(const float4*)(hr + kk * 32 + lk);
      float4 u1 = *(const float4*)(hr + kk * 32 + lk + 4);
      bf8 a;
      a[0] = (__bf16)u0.x; a[1] = (__bf16)u0.y;
      a[2] = (__bf16)u0.z; a[3] = (__bf16)u0.w;
      a[4] = (__bf16)u1.x; a[5] = (__bf16)u1.y;
      a[6] = (__bf16)u1.z; a[7] = (__bf16)u1.w;
      af[kk] = a;
    }
    f4 acc[8];
#pragma unroll
    for (int t = 0; t < 8; ++t) acc[t] = (f4){0.f, 0.f, 0.f, 0.f};
#pragma unroll
    for (int kk = 0; kk < 4; ++kk)
#pragma unroll
      for (int t = 0; t < 8; ++t)
        acc[t] = __builtin_amdgcn_mfma_f32_16x16x32_bf16(af[kk], wf[t][kk],
                                                         acc[t], 0, 0, 0);
    const int rbase = r0 + (lane >> 4) * 4;
#pragma unroll
    for (int t = 0; t < 8; ++t)
#pragma unroll
      for (int i = 0; i < 4; ++i) {
        int r = rbase + i;
        if (r < n_rows) tf[(size_t)r * F + t * 16 + lr] = (__bf16)acc[t][i];
      }
  }
}

// ---------------------- conflict-free aggregation of bf16 rows, + bias
// 32 lanes per node; lane c holds 4 bf16 (8B) of the 256B row.
__global__ __launch_bounds__(256) void aggregate_bf16(
    const __bf16* __restrict__ tf, const int* __restrict__ roff,
    const int* __restrict__ csr, const float* __restrict__ bias,
    float* __restrict__ out, int n_nodes) {
  long long gid = (long long)blockIdx.x * 256 + threadIdx.x;
  int node = (int)(gid >> 5);
  int c = (int)(gid & 31);
  if (node >= n_nodes) return;
  int beg = roff[node], end = roff[node + 1];
  const ushort4* t4 = (const ushort4*)tf;
  float4 b = ((const float4*)bias)[c];
  float ax = b.x, ay = b.y, az = b.z, aw = b.w;
  int k = beg;
  for (; k + 1 < end; k += 2) {
    int s0 = csr[k], s1 = csr[k + 1];
    ushort4 v0 = t4[(size_t)s0 * 32 + c];
    ushort4 v1 = t4[(size_t)s1 * 32 + c];
    ax += __uint_as_float((unsigned)v0.x << 16) + __uint_as_float((unsigned)v1.x << 16);
    ay += __uint_as_float((unsigned)v0.y << 16) + __uint_as_float((unsigned)v1.y << 16);
    az += __uint_as_float((unsigned)v0.z << 16) + __uint_as_float((unsigned)v1.z << 16);
    aw += __uint_as_float((unsigned)v0.w << 16) + __uint_as_float((unsigned)v1.w << 16);
  }
  if (k < end) {
    ushort4 v0 = t4[(size_t)csr[k] * 32 + c];
    ax += __uint_as_float((unsigned)v0.x << 16);
    ay += __uint_as_float((unsigned)v0.y << 16);
    az += __uint_as_float((unsigned)v0.z << 16);
    aw += __uint_as_float((unsigned)v0.w << 16);
  }
  ((float4*)out)[(size_t)node * 32 + c] = make_float4(ax, ay, az, aw);
}

// ---------------------------------------- R3 fallback path kernels (kept) ---
__global__ __launch_bounds__(256) void aggregate(
    const float* __restrict__ feat, const int* __restrict__ roff,
    const int* __restrict__ csr, float* __restrict__ h, int n_nodes) {
  long long gid = (long long)blockIdx.x * 256 + threadIdx.x;
  int node = (int)(gid >> 5);
  int c = (int)(gid & 31);
  if (node >= n_nodes) return;
  int beg = roff[node], end = roff[node + 1];
  float ax = 0.f, ay = 0.f, az = 0.f, aw = 0.f;
  const float4* f4p = (const float4*)feat;
  int k = beg;
  for (; k + 1 < end; k += 2) {
    int s0 = csr[k], s1 = csr[k + 1];
    float4 v0 = f4p[(size_t)s0 * 32 + c];
    float4 v1 = f4p[(size_t)s1 * 32 + c];
    ax += v0.x + v1.x;
    ay += v0.y + v1.y;
    az += v0.z + v1.z;
    aw += v0.w + v1.w;
  }
  if (k < end) {
    float4 v0 = f4p[(size_t)csr[k] * 32 + c];
    ax += v0.x; ay += v0.y; az += v0.z; aw += v0.w;
  }
  ((float4*)h)[(size_t)node * 32 + c] = make_float4(ax, ay, az, aw);
}

__global__ __launch_bounds__(256) void scatter_add(
    const float* __restrict__ feat, const int* __restrict__ src,
    const int* __restrict__ dst, float* __restrict__ h, int n_edges) {
  long long gid = (long long)blockIdx.x * 256 + threadIdx.x;
  int e = (int)(gid >> 5);
  if (e >= n_edges) return;
  int c = (int)(gid & 31);
  int s = src[e];
  int d = dst[e];
  float4 v = reinterpret_cast<const float4*>(feat + (long long)s * F)[c];
  float* hp = h + (long long)d * F + c * 4;
  __hip_atomic_fetch_add(hp + 0, v.x, __ATOMIC_RELAXED, __HIP_MEMORY_SCOPE_AGENT);
  __hip_atomic_fetch_add(hp + 1, v.y, __ATOMIC_RELAXED, __HIP_MEMORY_SCOPE_AGENT);
  __hip_atomic_fetch_add(hp + 2, v.z, __ATOMIC_RELAXED, __HIP_MEMORY_SCOPE_AGENT);
  __hip_atomic_fetch_add(hp + 3, v.w, __ATOMIC_RELAXED, __HIP_MEMORY_SCOPE_AGENT);
}

__global__ __launch_bounds__(256, 2) void gemm_bias_inplace(
    float* __restrict__ hout, const float* __restrict__ W,
    const float* __restrict__ bias, int n_rows, int n_groups) {
  const int lane = threadIdx.x & 63;
  const int wid = threadIdx.x >> 6;
  const int lr = lane & 15;
  const int lk = (lane >> 4) * 8;
  bf8 wf[8][4];
#pragma unroll
  for (int t = 0; t < 8; ++t) {
    const float* wr = W + (size_t)(t * 16 + lr) * F;
#pragma unroll
    for (int kk = 0; kk < 4; ++kk) {
      float4 u0 = *(const float4*)(wr + kk * 32 + lk);
      float4 u1 = *(const float4*)(wr + kk * 32 + lk + 4);
      bf8 b;
      b[0] = (__bf16)u0.x; b[1] = (__bf16)u0.y;
      b[2] = (__bf16)u0.z; b[3] = (__bf16)u0.w;
      b[4] = (__bf16)u1.x; b[5] = (__bf16)u1.y;
      b[6] = (__bf16)u1.z; b[7] = (__bf16)u1.w;
      wf[t][kk] = b;
    }
  }
  float bj[8];
#pragma unroll
  for (int t = 0; t < 8; ++t) bj[t] = bias[t * 16 + lr];
  for (int g = blockIdx.x; g < n_groups; g += gridDim.x) {
    const int r0 = g * 64 + wid * 16;
    if (r0 >= n_rows) continue;
    int arow = r0 + lr;
    if (arow >= n_rows) arow = n_rows - 1;
    const float* hr = hout + (size_t)arow * F;
    bf8 af[4];
#pragma unroll
    for (int kk = 0; kk < 4; ++kk) {
      float4 u0 = *(const float4*)(hr + kk * 32 + lk);
      float4 u1 = *(const float4*)(hr + kk * 32 + lk + 4);
      bf8 a;
      a[0] = (__bf16)u0.x; a[1] = (__bf16)u0.y;
      a[2] = (__bf16)u0.z; a[3] = (__bf16)u0.w;
      a[4] = (__bf16)u1.x; a[5] = (__bf16)u1.y;
      a[6] = (__bf16)u1.z; a[7] = (__bf16)u1.w;
      af[kk] = a;
    }
    f4 acc[8];
#pragma unroll
    for (int t = 0; t < 8; ++t) acc[t] = (f4){bj[t], bj[t], bj[t], bj[t]};
#pragma unroll
    for (int kk = 0; kk < 4; ++kk)
#pragma unroll
      for (int t = 0; t < 8; ++t)
        acc[t] = __builtin_amdgcn_mfma_f32_16x16x32_bf16(af[kk], wf[t][kk],
                                                         acc[t], 0, 0, 0);
    const int rbase = r0 + (lane >> 4) * 4;
#pragma unroll
    for (int t = 0; t < 8; ++t)
#pragma unroll
      for (int i = 0; i < 4; ++i) {
        int r = rbase + i;
        if (r < n_rows) hout[(size_t)r * F + t * 16 + lr] = acc[t][i];
      }
  }
}

static inline size_t align_up(size_t x, size_t a) { return (x + a - 1) & ~(a - 1); }

extern "C" void kernel_launch(void* const* d_in, const int* in_sizes, int n_in,
                              void* d_out, int out_size, void* d_ws, size_t ws_size,
                              hipStream_t stream) {
  const float* feat = (const float*)d_in[0];
  const int* esrc   = (const int*)d_in[1];
  const int* edst   = (const int*)d_in[2];
  const float* W    = (const float*)d_in[3];
  const float* bias = (const float*)d_in[4];
  float* out = (float*)d_out;

  const int nE = in_sizes[1];
  const int nN = out_size / F;  // 100000

  // workspace layout
  size_t off_deg  = 0;
  size_t off_roff = align_up(off_deg + (size_t)nN * 4, 256);
  size_t off_cur  = align_up(off_roff + ((size_t)nN + 1) * 4, 256);
  size_t off_bsum = align_up(off_cur + (size_t)nN * 4, 256);
  size_t off_csr  = align_up(off_bsum + 1024 * 4, 256);
  size_t off_tf   = align_up(off_csr + (size_t)nE * 4, 256);
  size_t need_csr = off_tf;                              // CSR-only path
  size_t need_all = off_tf + (size_t)nN * F * 2;         // + bf16 tfeat
  const int nb = (nN + SCAN_TILE - 1) / SCAN_TILE;
  const int n_groups = (nN + 63) / 64;

  if (ws_size >= need_csr && nb <= SCAN_BLK) {
    char* w = (char*)d_ws;
    int* deg  = (int*)(w + off_deg);
    int* roff = (int*)(w + off_roff);
    int* cur  = (int*)(w + off_cur);
    int* bsum = (int*)(w + off_bsum);
    int* csr  = (int*)(w + off_csr);

    const bool fused = (ws_size >= need_all);
    __bf16* tf = (__bf16*)(w + off_tf);

    if (fused)  // transform first; overlaps nothing but is independent of CSR
      transform_bf16<<<640, 256, 0, stream>>>(feat, W, tf, nN, n_groups);

    zero_int<<<(nN + 255) / 256, 256, 0, stream>>>(deg, nN);
    count_deg<<<(nE + 255) / 256, 256, 0, stream>>>(edst, deg, nE);
    scan1<<<nb, SCAN_BLK, 0, stream>>>(deg, roff, bsum, nN);
    scan2<<<1, SCAN_BLK, 0, stream>>>(bsum, nb);
    scan3<<<(nN + 255) / 256, 256, 0, stream>>>(roff, cur, bsum, nN, nE);
    build_csr<<<(nE + 255) / 256, 256, 0, stream>>>(esrc, edst, cur, csr, nE);

    long long thr = (long long)nN * 32;
    int ablocks = (int)((thr + 255) / 256);
    if (fused) {
      aggregate_bf16<<<ablocks, 256, 0, stream>>>(tf, roff, csr, bias, out, nN);
    } else {
      aggregate<<<ablocks, 256, 0, stream>>>(feat, roff, csr, out, nN);
      gemm_bias_inplace<<<640, 256, 0, stream>>>(out, W, bias, nN, n_groups);
    }
  } else {
    int n4 = out_size / 4;
    zero_f4<<<(n4 + 255) / 256, 256, 0, stream>>>((float4*)out, n4);
    long long total = (long long)nE * 32;
    scatter_add<<<(int)((total + 255) / 256), 256, 0, stream>>>(feat, esrc,
                                                                edst, out, nE);
    gemm_bias_inplace<<<640, 256, 0, stream>>>(out, W, bias, nN, n_groups);
  }
}